// Round 2
// baseline (1647.371 us; speedup 1.0000x reference)
//
#include <hip/hip_runtime.h>
#include <stdint.h>

#define NA 50000          // atoms
#define DD 256            // embedding
#define NF 4              // formulas
#define NG 50000          // groundings (cliques) per formula
#define AA 3              // atoms per clique
#define MM (NG * AA)      // 150000 rows per formula
#define KK 512            // 2*D
#define BM 96             // divisible by 3 -> clique groups never split across tiles
#define BN 128
#define BK 64
#define MT ((MM + BM - 1) / BM)   // 1563

typedef __attribute__((ext_vector_type(8))) short s16x8;
typedef __attribute__((ext_vector_type(4))) float f32x4;

__device__ __forceinline__ unsigned short f2bf(float f) {
  union { float f; uint32_t u; } v; v.f = f;
  return (unsigned short)((v.u + 0x7FFFu + ((v.u >> 16) & 1u)) >> 16);  // RNE
}

__device__ __forceinline__ void gld_lds16(const void* g, void* l) {
  // async 16B/lane global->LDS; LDS dest = uniform base + lane*16, global src per-lane
  __builtin_amdgcn_global_load_lds(
      (const __attribute__((address_space(1))) uint32_t*)g,
      (__attribute__((address_space(3))) uint32_t*)l, 16, 0, 0);
}

// f32 -> bf16, 4 elems/thread
__global__ void cvt_f32_bf16(const float* __restrict__ src, unsigned short* __restrict__ dst, int n4) {
  int i = blockIdx.x * 256 + threadIdx.x;
  if (i < n4) {
    const float4 v = ((const float4*)src)[i];
    union { unsigned short s[4]; uint2 u; } o;
    o.s[0] = f2bf(v.x); o.s[1] = f2bf(v.y); o.s[2] = f2bf(v.z); o.s[3] = f2bf(v.w);
    ((uint2*)dst)[i] = o.u;
  }
}

// Build bf16 weights in PRE-CHUNKED k-major slot order so each staging
// global_load_lds instruction reads a contiguous 1KB block.
// Slot order: [f][nb][kb][s=0..1023], slot s holds 8 bf16 of
//   n = nb*128 + (s&127), k = kb*64 + (s>>7)*8 .. +7
// Wt0: layer 0, NB=4 (n<256 -> W_M[0], else W_U[0]); Wt1: layer 1, NB=2 (W_U[1]).
__global__ void prep_w(const float* __restrict__ WM, const float* __restrict__ WU,
                       unsigned short* __restrict__ Wt0, unsigned short* __restrict__ Wt1) {
  const int slots0 = NF * 4 * 8 * 1024;        // 131072
  const int slots1 = NF * 2 * 8 * 1024;        // 65536
  int t = blockIdx.x * 256 + threadIdx.x;
  const float* src;
  int n, k, f;
  unsigned short* dst;
  if (t < slots0) {
    f = t >> 15;
    int rem = t & 32767;
    int nb = rem >> 13, rem2 = rem & 8191;
    int kb = rem2 >> 10, s = rem2 & 1023;
    n = nb * 128 + (s & 127);
    k = kb * 64 + (s >> 7) * 8;
    if (n < 256) { src = WM + ((size_t)f * 512) * 256 + n; }
    else         { src = WU + ((size_t)f * 512) * 256 + (n - 256); }
    dst = Wt0 + (size_t)t * 8;
  } else if (t < slots0 + slots1) {
    int u2 = t - slots0;
    f = u2 >> 14;
    int rem = u2 & 16383;
    int nb = rem >> 13, rem2 = rem & 8191;
    int kb = rem2 >> 10, s = rem2 & 1023;
    n = nb * 128 + (s & 127);
    k = kb * 64 + (s >> 7) * 8;
    src = WU + ((size_t)(NF + f) * 512) * 256 + n;
    dst = Wt1 + (size_t)u2 * 8;
  } else return;
  union { unsigned short h[8]; uint4 u; } o;
#pragma unroll
  for (int e = 0; e < 8; ++e) o.h[e] = f2bf(src[(size_t)(k + e) * 256]);
  *(uint4*)dst = o.u;
}

// Fused gather-GEMM with per-layer epilogue.
// A row m (global r = m0+m): cols 0..255 from atomSrc[gIdx[f,r]], cols 256..511 from gclSrc[f, r/3]
// LDS layout (k-major chunked): slot = chunk*ROWS + row, 16B per slot.
//   -> fragment reads are 256B-contiguous per 16-lane group: zero bank conflicts.
template <int LAYER>
__global__ __launch_bounds__(256, 2)
void fgnn_gemm(const unsigned short* __restrict__ atomSrc,
               const unsigned short* __restrict__ gclSrc,
               const unsigned short* __restrict__ Wt,
               const int* __restrict__ gIdx,
               const float* __restrict__ bM,
               const float* __restrict__ bU,
               float* __restrict__ atomOut,          // f32 scatter-max target (u32 atomics)
               unsigned short* __restrict__ gclOut)  // bf16 [F*G][256] (layer 0, nt<2)
{
  constexpr int NOUT = (LAYER == 0) ? 512 : 256;
  constexpr int NB = NOUT / BN;
  const int mt = blockIdx.x, nt = blockIdx.y, f = blockIdx.z;
  const int m0 = mt * BM;
  const int tid = threadIdx.x;
  const int lane = tid & 63, wid = tid >> 6;
  const int wm = wid >> 1, wn = wid & 1;   // 2x2 wave grid: 48 rows x 64 cols per wave

  __shared__ union U {
    struct { unsigned short A[2][BM * BK]; unsigned short B[2][BN * BK]; } s;  // 24KB + 32KB
    float gc[BM * 130];                                                         // 48.8KB epilogue reuse
  } u;
  __shared__ int idx_lds[BM];

  if (tid < BM) {
    int r = m0 + tid; if (r > MM - 1) r = MM - 1;
    idx_lds[tid] = gIdx[(size_t)f * MM + r];
  }
  __syncthreads();

  // ---- staging source pointers (k-major chunk layout; LDS dest linear per inst) ----
  // A: 12 insts, inst q = j*4+wid covers slots s = q*64+lane; s -> row = s%96, c = s/96
  const unsigned short* paA[3];  // atom half (k0 < 256)
  const unsigned short* paG[3];  // gcl half  (k0 >= 256)
#pragma unroll
  for (int j = 0; j < 3; ++j) {
    int s = (j * 4 + wid) * 64 + lane;               // 0..767
    int c = (s * 1366) >> 17;                        // s / 96
    int row = s - c * 96;
    int r = m0 + row; if (r > MM - 1) r = MM - 1;
    int idx = idx_lds[row];
    int g = r / 3;
    paA[j] = atomSrc + (size_t)idx * DD + c * 8;
    paG[j] = gclSrc + ((size_t)f * NG + g) * DD + c * 8;
  }
  // B: 16 insts, inst q = j*4+wid covers slots s = q*64+lane (pre-chunked global: contiguous!)
  const unsigned short* pB[4];
  {
    const unsigned short* WtBlk = Wt + ((size_t)(f * NB + nt) * 8) * 8192;
#pragma unroll
    for (int j = 0; j < 4; ++j) {
      int s = (j * 4 + wid) * 64 + lane;
      pB[j] = WtBlk + (size_t)s * 8;
    }
  }

  auto stage = [&](int buf, int ks) {
    int k0 = ks * BK;
#pragma unroll
    for (int j = 0; j < 3; ++j) {
      const unsigned short* src = (k0 < DD) ? (paA[j] + k0) : (paG[j] + (k0 - DD));
      gld_lds16(src, &u.s.A[buf][(j * 4 + wid) * 512]);
    }
#pragma unroll
    for (int j = 0; j < 4; ++j)
      gld_lds16(pB[j] + (size_t)ks * 8192, &u.s.B[buf][(j * 4 + wid) * 512]);
  };

  f32x4 acc[3][4];
#pragma unroll
  for (int m = 0; m < 3; ++m)
#pragma unroll
    for (int n = 0; n < 4; ++n) acc[m][n] = (f32x4)0.f;

  stage(0, 0);
  int cur = 0;
  const int hi = lane >> 4, lo = lane & 15;
  for (int ks = 0; ks < KK / BK; ++ks) {
    __syncthreads();                                  // drains vmcnt: buf[cur] staged & prior reads done
    if (ks + 1 < KK / BK) stage(cur ^ 1, ks + 1);
#pragma unroll
    for (int kk = 0; kk < 2; ++kk) {
      s16x8 af[3], bf4[4];
      int cA = (kk * 4 + hi) * 96;                    // chunk base (A slots)
      int cB = (kk * 4 + hi) * 128;                   // chunk base (B slots)
#pragma unroll
      for (int m = 0; m < 3; ++m)
        af[m] = *(const s16x8*)&u.s.A[cur][(cA + wm * 48 + m * 16 + lo) * 8];
#pragma unroll
      for (int n = 0; n < 4; ++n)
        bf4[n] = *(const s16x8*)&u.s.B[cur][(cB + wn * 64 + n * 16 + lo) * 8];
#pragma unroll
      for (int m = 0; m < 3; ++m)
#pragma unroll
        for (int n = 0; n < 4; ++n)
          acc[m][n] = __builtin_amdgcn_mfma_f32_16x16x32_bf16(af[m], bf4[n], acc[m][n], 0, 0, 0);
    }
    cur ^= 1;
  }

  // ---- epilogue ----
  if (LAYER == 0 && nt < 2) {
    // message path: relu(+b_M) -> max over the 3 rows of each clique -> gclOut (bf16, plain stores)
    float bias_n[4];
#pragma unroll
    for (int n = 0; n < 4; ++n)
      bias_n[n] = bM[f * DD + nt * BN + wn * 64 + n * 16 + lo];
    __syncthreads();                                  // done with staging LDS
#pragma unroll
    for (int m = 0; m < 3; ++m)
#pragma unroll
      for (int n = 0; n < 4; ++n) {
        int col = wn * 64 + n * 16 + lo;
#pragma unroll
        for (int r = 0; r < 4; ++r) {
          int row = wm * 48 + m * 16 + (hi << 2) + r;  // C/D: col=lane&15, row=(lane>>4)*4+reg
          u.gc[row * 130 + col] = fmaxf(acc[m][n][r] + bias_n[n], 0.f);
        }
      }
    __syncthreads();
    int nvg = ((MM - m0 < BM) ? (MM - m0) : BM) / 3;
    for (int e = tid; e < 32 * BN; e += 256) {
      int grp = e >> 7, col = e & 127;
      if (grp < nvg) {
        float v = fmaxf(fmaxf(u.gc[(grp * 3 + 0) * 130 + col],
                              u.gc[(grp * 3 + 1) * 130 + col]),
                        u.gc[(grp * 3 + 2) * 130 + col]);
        gclOut[((size_t)f * NG + (size_t)(m0 / 3 + grp)) * DD + nt * BN + col] = f2bf(v);
      }
    }
  } else {
    // update path: relu(+b_U) -> scatter-max into atomOut via u32 atomicMax (values >= 0)
    const float* bp; int coloff;
    if (LAYER == 0) { bp = bU + f * DD;        coloff = (nt - 2) * BN; }
    else            { bp = bU + (NF + f) * DD; coloff = nt * BN; }
    float bias_n[4];
#pragma unroll
    for (int n = 0; n < 4; ++n)
      bias_n[n] = bp[coloff + wn * 64 + n * 16 + lo];
#pragma unroll
    for (int m = 0; m < 3; ++m)
#pragma unroll
      for (int r = 0; r < 4; ++r) {
        int rl = wm * 48 + m * 16 + (hi << 2) + r;
        if (m0 + rl < MM) {
          int idx = idx_lds[rl];
#pragma unroll
          for (int n = 0; n < 4; ++n) {
            int col = coloff + wn * 64 + n * 16 + lo;
            float v = fmaxf(acc[m][n][r] + bias_n[n], 0.f);
            atomicMax((unsigned int*)&atomOut[(size_t)idx * DD + col], __float_as_uint(v));
          }
        }
      }
  }
}

extern "C" void kernel_launch(void* const* d_in, const int* in_sizes, int n_in,
                              void* d_out, int out_size, void* d_ws, size_t ws_size,
                              hipStream_t stream) {
  const float* x  = (const float*)d_in[0];
  const int*   gi = (const int*)d_in[1];
  const float* fg = (const float*)d_in[2];
  const float* WM = (const float*)d_in[3];
  const float* bM = (const float*)d_in[4];
  const float* WU = (const float*)d_in[5];
  const float* bU = (const float*)d_in[6];
  float* out = (float*)d_out;

  char* ws = (char*)d_ws;
  size_t off = 0;
  auto alloc = [&](size_t b) { char* p = ws + off; off += (b + 255) & ~(size_t)255; return p; };
  unsigned short* gcl0  = (unsigned short*)alloc((size_t)NF * NG * DD * 2);   // 102.4 MB
  unsigned short* gcl1  = (unsigned short*)alloc((size_t)NF * NG * DD * 2);   // 102.4 MB
  unsigned short* atomB = (unsigned short*)alloc((size_t)NA * DD * 2);        // 25.6 MB
  unsigned short* Wt0   = (unsigned short*)alloc((size_t)NF * 512 * 512 * 2); // 2 MB
  unsigned short* Wt1   = (unsigned short*)alloc((size_t)NF * 256 * 512 * 2); // 1 MB

  // d_out doubles as the f32 layer-0 scatter target (atom1), then is re-zeroed for layer 1.
  hipMemsetAsync(d_out, 0, (size_t)NA * DD * 4, stream);

  cvt_f32_bf16<<<(NA * DD / 4 + 255) / 256, 256, 0, stream>>>(x, atomB, NA * DD / 4);
  cvt_f32_bf16<<<(NF * NG * DD / 4 + 255) / 256, 256, 0, stream>>>(fg, gcl0, NF * NG * DD / 4);
  prep_w<<<((NF * 4 * 8 * 1024 + NF * 2 * 8 * 1024) + 255) / 256, 256, 0, stream>>>(WM, WU, Wt0, Wt1);

  fgnn_gemm<0><<<dim3(MT, 4, NF), 256, 0, stream>>>(atomB, gcl0, Wt0, gi, bM, bU, out, gcl1);

  cvt_f32_bf16<<<(NA * DD / 4 + 255) / 256, 256, 0, stream>>>(out, atomB, NA * DD / 4);  // atom1 -> bf16
  hipMemsetAsync(d_out, 0, (size_t)NA * DD * 4, stream);

  fgnn_gemm<1><<<dim3(MT, 2, NF), 256, 0, stream>>>(atomB, gcl1, Wt1, gi, bM, bU, out, nullptr);
}